// Round 7
// baseline (181.331 us; speedup 1.0000x reference)
//
#include <hip/hip_runtime.h>
#include <math.h>

// out[b,p] = || (I - U_p U_p^T)(x_b - proto_p) ||,  B=1024 P=200 D=512 S=64
// t = U^T x - c, c = U^T proto; ||y||^2 = q - 2||t||^2 + t^T G t,
// q = ||x||^2 - 2 x.proto + ||proto||^2, G = U^T U (symmetric).
// GEMM1 (X@[U|proto]) + GEMM2 (H=t@G) in bf16 MFMA; tn=||t||^2 fp32 exact.
// k_main is BARRIER-FREE in the K-loop: MFMA fragments load straight from
// global (L2-resident working set; compiler emits counted vmcnt, no drain).

#define NB 1024
#define NP 200
#define ND 512
#define NS 64
#define NS5 80   // 64 U-cols + proto col + 15 pad rows (never consumed)

// ws float offsets; total 4,785,864 floats (~19.2 MB) incl. 16-row overrun pad
#define OFF_C   0          // fp32 [200][64]  c = U^T proto
#define OFF_PN  12800      // fp32 [200]      ||proto||^2
#define OFF_XN  13000      // fp32 [1024]     ||x||^2
#define OFF_GB  14024      // bf16 [200][64][64]  G
#define OFF_XB  423624     // bf16 [1024][512]
#define OFF_UB  685768     // bf16 [200][80][512] (U^T | proto | junk)

typedef __attribute__((ext_vector_type(8))) short bf16x8;
typedef __attribute__((ext_vector_type(8))) unsigned short ushort8;
typedef __attribute__((ext_vector_type(4))) float f32x4;

__device__ __forceinline__ unsigned short f2bf(float f) {
  unsigned int u = __float_as_uint(f);
  u += 0x7fffu + ((u >> 16) & 1u);   // RNE
  return (unsigned short)(u >> 16);
}
__device__ __forceinline__ float bf2f(unsigned short h) {
  return __uint_as_float(((unsigned int)h) << 16);
}

// ---------------------------------------------------------------------------
// k_conv: grid 832. Blocks 0..799: transpose+convert U chunk (p = bid>>2,
// 128 d-rows) -> Ub bf16 [p][s][d] + proto row-64 segment. Blocks 800..831:
// convert 32 rows of x -> Xb bf16 + ||x||^2.
// ---------------------------------------------------------------------------
__global__ __launch_bounds__(256) void k_conv(
    const float* __restrict__ x, const float* __restrict__ protos,
    const float* __restrict__ U, float* __restrict__ ws)
{
  const int bid = blockIdx.x, tid = threadIdx.x;
  if (bid >= 800) {
    const int b = (bid - 800) * 32 + (tid >> 3);
    const int cc = tid & 7;
    const float* src = x + (size_t)b * ND + cc * 64;
    unsigned short* dst = (unsigned short*)(ws + OFF_XB) + (size_t)b * ND + cc * 64;
    float s = 0.f;
#pragma unroll
    for (int i = 0; i < 8; ++i) {
      float4 v0 = *(const float4*)(src + i * 8);
      float4 v1 = *(const float4*)(src + i * 8 + 4);
      ushort8 o;
      o[0]=f2bf(v0.x); o[1]=f2bf(v0.y); o[2]=f2bf(v0.z); o[3]=f2bf(v0.w);
      o[4]=f2bf(v1.x); o[5]=f2bf(v1.y); o[6]=f2bf(v1.z); o[7]=f2bf(v1.w);
      *(ushort8*)(dst + i * 8) = o;
      s += v0.x*v0.x + v0.y*v0.y + v0.z*v0.z + v0.w*v0.w
         + v1.x*v1.x + v1.y*v1.y + v1.z*v1.z + v1.w*v1.w;
    }
    s += __shfl_xor(s, 1); s += __shfl_xor(s, 2); s += __shfl_xor(s, 4);
    if (cc == 0) ws[OFF_XN + b] = s;
    return;
  }
  const int p = bid >> 2, d0 = (bid & 3) * 128;
  __shared__ unsigned short ts[128][66];   // bf16, pad 66: column reads 2-way
#pragma unroll
  for (int i = 0; i < 8; ++i) {
    int row = (tid >> 4) + i * 16;
    int col = (tid & 15) * 4;
    float4 v = *(const float4*)(U + ((size_t)p * ND + d0 + row) * NS + col);
    ts[row][col] = f2bf(v.x); ts[row][col+1] = f2bf(v.y);
    ts[row][col+2] = f2bf(v.z); ts[row][col+3] = f2bf(v.w);
  }
  __syncthreads();
  unsigned short* Ubg = (unsigned short*)(ws + OFF_UB) + (size_t)p * NS5 * ND;
#pragma unroll
  for (int i = 0; i < 4; ++i) {
    int f = tid + i * 256;               // 1024 granules: s = f>>4, g = f&15
    int s = f >> 4, g = f & 15;
    ushort8 o;
#pragma unroll
    for (int j = 0; j < 8; ++j) o[j] = ts[g * 8 + j][s];
    *(ushort8*)(Ubg + (size_t)s * ND + d0 + g * 8) = o;
  }
  if (tid < 16) {                        // proto row 64, this d-chunk
    const float* pr = protos + (size_t)p * ND + d0 + tid * 8;
    float4 v0 = *(const float4*)pr, v1 = *(const float4*)(pr + 4);
    ushort8 o;
    o[0]=f2bf(v0.x); o[1]=f2bf(v0.y); o[2]=f2bf(v0.z); o[3]=f2bf(v0.w);
    o[4]=f2bf(v1.x); o[5]=f2bf(v1.y); o[6]=f2bf(v1.z); o[7]=f2bf(v1.w);
    *(ushort8*)(Ubg + (size_t)64 * ND + d0 + tid * 8) = o;
  }
}

// ---------------------------------------------------------------------------
// k_gram: Ghat = Ub @ Ub^T via MFMA. 4x4 tiles -> Gb bf16; col 4 -> c fp32;
// (4,4) diag -> pn. grid 200 x 256. 80 KB LDS, granule-swizzled.
// ---------------------------------------------------------------------------
__global__ __launch_bounds__(256) void k_gram(float* __restrict__ ws) {
  const int p = blockIdx.x;
  __shared__ __align__(16) unsigned short ut[NS5 * ND];  // 80 KB
  const int tid = threadIdx.x, l = tid & 63, w = tid >> 6;
  const int lm = l & 15, lh = l >> 4;
  const unsigned short* ub =
      (const unsigned short*)(ws + OFF_UB) + (size_t)p * NS5 * ND;
  // LDS granule f holds data granule (f&63)^(row&15) of row f>>6
#pragma unroll
  for (int i = 0; i < 20; ++i) {
    int f = tid + i * 256;
    int r = f >> 6;
    int gd = (f & 63) ^ (r & 15);
    *(ushort8*)(ut + (size_t)f * 8) = *(const ushort8*)(ub + (size_t)r * ND + gd * 8);
  }
  __syncthreads();
  const int ntile = (w == 0) ? 6 : 5;
  for (int idx = 0; idx < ntile; ++idx) {
    int tt = (idx == 5) ? 20 : (w + 4 * idx);
    int i1 = (tt == 20) ? 4 : tt / 5;
    int i2 = (tt == 20) ? 4 : tt % 5;
    f32x4 g = {0.f, 0.f, 0.f, 0.f};
#pragma unroll
    for (int ks = 0; ks < 16; ++ks) {
      int sl = (ks * 4 + lh) ^ lm;
      bf16x8 a = *(const bf16x8*)(ut + ((size_t)(i1 * 16 + lm) * 64 + sl) * 8);
      bf16x8 b = *(const bf16x8*)(ut + ((size_t)(i2 * 16 + lm) * 64 + sl) * 8);
      g = __builtin_amdgcn_mfma_f32_16x16x32_bf16(a, b, g, 0, 0, 0);
    }
    int col = i2 * 16 + lm;
    int row0 = i1 * 16 + lh * 4;
    if (i1 < 4 && i2 < 4) {
      unsigned short* Gbg = (unsigned short*)(ws + OFF_GB) + (size_t)p * 4096;
#pragma unroll
      for (int q = 0; q < 4; ++q) Gbg[(size_t)(row0 + q) * 64 + col] = f2bf(g[q]);
    } else if (i1 < 4 && i2 == 4 && lm == 0) {
#pragma unroll
      for (int q = 0; q < 4; ++q) ws[OFF_C + p * 64 + row0 + q] = g[q];
    } else if (tt == 20 && l == 0) {
      ws[OFF_PN + p] = g[0];
    }
  }
}

// ---------------------------------------------------------------------------
// k_main: grid (200, 8) [all 8 row-tiles of p on one XCD; 3.2 MB/XCD in L2].
// GEMM1: MFMA fragments loaded DIRECTLY from global (no LDS staging, no
// K-loop barriers -> compiler emits counted vmcnt). Epilogue: t -> tb bf16
// (LDS), tn fp32 exact; GEMM2 H = tb@Gb MFMA; out. LDS 28.4 KB -> 5 blk/CU.
// ---------------------------------------------------------------------------
__global__ __launch_bounds__(256) void k_main(float* __restrict__ ws,
                                              float* __restrict__ out)
{
  const int p = blockIdx.x;
  const int b0 = blockIdx.y * 128;
  __shared__ __align__(16) char smem[28416];
  unsigned short* tb = (unsigned short*)smem;             // [128][72] bf16
  unsigned short* gs = (unsigned short*)(smem + 18432);   // [64][72] bf16 G
  float* cs  = (float*)(smem + 27648);                    // [64]
  float* xps = (float*)(smem + 27904);                    // [128]
  const int tid = threadIdx.x, l = tid & 63, w = tid >> 6;
  const int lm = l & 15, lh = l >> 4;

  // stage G + c into LDS (visible after the one barrier below)
  {
    const unsigned short* Gbg = (const unsigned short*)(ws + OFF_GB) + (size_t)p * 4096;
#pragma unroll
    for (int i = 0; i < 2; ++i) {
      int f = tid + i * 256;
      int r = f >> 3, g = f & 7;
      *(ushort8*)(gs + (size_t)r * 72 + g * 8) =
          *(const ushort8*)(Gbg + (size_t)r * 64 + g * 8);
    }
    if (tid < 16)
      *(float4*)(cs + tid * 4) = *(const float4*)(ws + OFF_C + p * 64 + tid * 4);
  }

  const unsigned short* Xb = (const unsigned short*)(ws + OFF_XB) + (size_t)b0 * ND;
  const unsigned short* Ub = (const unsigned short*)(ws + OFF_UB) + (size_t)p * NS5 * ND;
  // per-lane row bases (wave w owns rows 32w..32w+31; Ub rows shared)
  const unsigned short* xr0 = Xb + (size_t)((w * 2 + 0) * 16 + lm) * ND;
  const unsigned short* xr1 = Xb + (size_t)((w * 2 + 1) * 16 + lm) * ND;
  const unsigned short* ur  = Ub + (size_t)lm * ND;

  // ---- GEMM1: no barriers; 14 b128 loads + 20 MFMA per K-tile ----
  f32x4 acc[2][5] = {};
#pragma unroll 2
  for (int it = 0; it < 8; ++it) {
    const int k0 = it * 64;
#pragma unroll
    for (int ks = 0; ks < 2; ++ks) {
      const int kc = k0 + ks * 32 + lh * 8;
      bf16x8 a0 = *(const bf16x8*)(xr0 + kc);
      bf16x8 a1 = *(const bf16x8*)(xr1 + kc);
#pragma unroll
      for (int j = 0; j < 5; ++j) {
        bf16x8 b = *(const bf16x8*)(ur + (size_t)j * 16 * ND + kc);
        acc[0][j] = __builtin_amdgcn_mfma_f32_16x16x32_bf16(a0, b, acc[0][j], 0, 0, 0);
        acc[1][j] = __builtin_amdgcn_mfma_f32_16x16x32_bf16(a1, b, acc[1][j], 0, 0, 0);
      }
    }
  }
  __syncthreads();   // gs/cs visibility (the only barrier in this kernel)

  // ---- epilogue 1: t = acc - c -> tb bf16; tn fp32 exact; xps ----
  float tn[2][4] = {};
#pragma unroll
  for (int i = 0; i < 2; ++i) {
    int rbase = (w * 2 + i) * 16 + lh * 4;
#pragma unroll
    for (int j = 0; j < 5; ++j) {
      f32x4 v = acc[i][j];
      if (j < 4) {
        int col = j * 16 + lm;
        float cj = cs[col];
#pragma unroll
        for (int q = 0; q < 4; ++q) {
          float t = v[q] - cj;
          tn[i][q] += t * t;
          tb[(size_t)(rbase + q) * 72 + col] = f2bf(t);
        }
      } else if (lm == 0) {
#pragma unroll
        for (int q = 0; q < 4; ++q) xps[rbase + q] = v[q];
      }
    }
  }
  // tb rows are wave-private (written+read by the same wave): no barrier.

  // ---- GEMM2: H = tb @ G (B-frag = G rows, G symmetric) ----
  f32x4 acc2[2][4] = {};
#pragma unroll
  for (int ks = 0; ks < 2; ++ks) {
#pragma unroll
    for (int i = 0; i < 2; ++i) {
      bf16x8 a = *(const bf16x8*)(tb + (size_t)((w*2+i)*16 + lm) * 72 + ks*32 + lh*8);
#pragma unroll
      for (int j = 0; j < 4; ++j) {
        bf16x8 b = *(const bf16x8*)(gs + (size_t)(j*16 + lm) * 72 + ks*32 + lh*8);
        acc2[i][j] = __builtin_amdgcn_mfma_f32_16x16x32_bf16(a, b, acc2[i][j], 0, 0, 0);
      }
    }
  }

  // ---- tgt = sum_s2 H*t; reduce over lm; out = sqrt(q - 2tn + tgt) ----
  const float pnv = ws[OFF_PN + p];
#pragma unroll
  for (int i = 0; i < 2; ++i) {
    int rbase = (w * 2 + i) * 16 + lh * 4;
    float tgt[4] = {0.f, 0.f, 0.f, 0.f};
#pragma unroll
    for (int j = 0; j < 4; ++j) {
      int col = j * 16 + lm;
#pragma unroll
      for (int q = 0; q < 4; ++q)
        tgt[q] += acc2[i][j][q] * bf2f(tb[(size_t)(rbase + q) * 72 + col]);
    }
#pragma unroll
    for (int q = 0; q < 4; ++q) {
      float ta = tgt[q], tnv = tn[i][q];
#pragma unroll
      for (int m = 1; m <= 8; m <<= 1) {
        ta += __shfl_xor(ta, m);
        tnv += __shfl_xor(tnv, m);
      }
      tgt[q] = ta; tn[i][q] = tnv;
    }
    if (lm == 0) {
#pragma unroll
      for (int q = 0; q < 4; ++q) {
        int r = rbase + q;
        int bb = b0 + r;
        float qq = ws[OFF_XN + bb] - 2.f * xps[r] + pnv;
        float v = qq - 2.f * tn[i][q] + tgt[q];
        out[(size_t)bb * NP + p] = sqrtf(fmaxf(v, 0.f));
      }
    }
  }
}

// ---------------------------------------------------------------------------
extern "C" void kernel_launch(void* const* d_in, const int* in_sizes, int n_in,
                              void* d_out, int out_size, void* d_ws, size_t ws_size,
                              hipStream_t stream) {
  const float* x      = (const float*)d_in[0];
  const float* protos = (const float*)d_in[1];
  const float* U      = (const float*)d_in[2];
  float* out = (float*)d_out;
  float* ws  = (float*)d_ws;   // needs 4,785,864 floats (~19.2 MB)

  k_conv<<<dim3(832),   dim3(256), 0, stream>>>(x, protos, U, ws);
  k_gram<<<dim3(NP),    dim3(256), 0, stream>>>(ws);
  k_main<<<dim3(NP, 8), dim3(256), 0, stream>>>(ws, out);
}

// Round 8
// 130.663 us; speedup vs baseline: 1.3878x; 1.3878x over previous
//
#include <hip/hip_runtime.h>
#include <math.h>

// out[b,p] = || (I - U_p U_p^T)(x_b - proto_p) ||,  B=1024 P=200 D=512 S=64
// t = U^T x - c, c = U^T proto; ||y||^2 = q - 2||t||^2 + t^T G t,
// q = ||x||^2 - 2 x.proto + ||proto||^2, G = U^T U (symmetric).
// k_main: Ub staged ONCE into LDS (72 KB, swizzled, gl_lds); K-loop has zero
// barriers -- A-fragments stream from L2 (counted vmcnt), B via ds_read
// (lgkmcnt), 20 MFMA/step. G + c live in registers. One barrier total.

#define NB 1024
#define NP 200
#define ND 512
#define NS 64
#define NS5 80   // 64 U-cols + proto col + pad rows

// ws float offsets; total 4,785,864 floats (~19.2 MB) incl. 16-row overrun pad
#define OFF_C   0          // fp32 [200][64]  c = U^T proto
#define OFF_PN  12800      // fp32 [200]      ||proto||^2
#define OFF_XN  13000      // fp32 [1024]     ||x||^2
#define OFF_GB  14024      // bf16 [200][64][64]  G
#define OFF_XB  423624     // bf16 [1024][512]
#define OFF_UB  685768     // bf16 [200][80][512] (U^T | proto | junk)

typedef __attribute__((ext_vector_type(8))) short bf16x8;
typedef __attribute__((ext_vector_type(8))) unsigned short ushort8;
typedef __attribute__((ext_vector_type(4))) float f32x4;

__device__ __forceinline__ unsigned short f2bf(float f) {
  unsigned int u = __float_as_uint(f);
  u += 0x7fffu + ((u >> 16) & 1u);   // RNE
  return (unsigned short)(u >> 16);
}
__device__ __forceinline__ float bf2f(unsigned short h) {
  return __uint_as_float(((unsigned int)h) << 16);
}
// async global->LDS, 16B/lane; LDS dest = wave-uniform base + lane*16
__device__ __forceinline__ void gl_lds16(const void* g, void* l) {
  __builtin_amdgcn_global_load_lds(
      (const __attribute__((address_space(1))) unsigned int*)g,
      (__attribute__((address_space(3))) unsigned int*)l, 16, 0, 0);
}

// ---------------------------------------------------------------------------
// k_conv: grid 832. Blocks 0..799: transpose+convert U chunk (p = bid>>2,
// 128 d-rows) -> Ub bf16 [p][s][d] + proto row-64 segment. Blocks 800..831:
// convert 32 rows of x -> Xb bf16 + ||x||^2.   (unchanged from round 6)
// ---------------------------------------------------------------------------
__global__ __launch_bounds__(256) void k_conv(
    const float* __restrict__ x, const float* __restrict__ protos,
    const float* __restrict__ U, float* __restrict__ ws)
{
  const int bid = blockIdx.x, tid = threadIdx.x;
  if (bid >= 800) {
    const int b = (bid - 800) * 32 + (tid >> 3);
    const int cc = tid & 7;
    const float* src = x + (size_t)b * ND + cc * 64;
    unsigned short* dst = (unsigned short*)(ws + OFF_XB) + (size_t)b * ND + cc * 64;
    float s = 0.f;
#pragma unroll
    for (int i = 0; i < 8; ++i) {
      float4 v0 = *(const float4*)(src + i * 8);
      float4 v1 = *(const float4*)(src + i * 8 + 4);
      ushort8 o;
      o[0]=f2bf(v0.x); o[1]=f2bf(v0.y); o[2]=f2bf(v0.z); o[3]=f2bf(v0.w);
      o[4]=f2bf(v1.x); o[5]=f2bf(v1.y); o[6]=f2bf(v1.z); o[7]=f2bf(v1.w);
      *(ushort8*)(dst + i * 8) = o;
      s += v0.x*v0.x + v0.y*v0.y + v0.z*v0.z + v0.w*v0.w
         + v1.x*v1.x + v1.y*v1.y + v1.z*v1.z + v1.w*v1.w;
    }
    s += __shfl_xor(s, 1); s += __shfl_xor(s, 2); s += __shfl_xor(s, 4);
    if (cc == 0) ws[OFF_XN + b] = s;
    return;
  }
  const int p = bid >> 2, d0 = (bid & 3) * 128;
  __shared__ unsigned short ts[128][66];   // bf16, pad 66: column reads 2-way
#pragma unroll
  for (int i = 0; i < 8; ++i) {
    int row = (tid >> 4) + i * 16;
    int col = (tid & 15) * 4;
    float4 v = *(const float4*)(U + ((size_t)p * ND + d0 + row) * NS + col);
    ts[row][col] = f2bf(v.x); ts[row][col+1] = f2bf(v.y);
    ts[row][col+2] = f2bf(v.z); ts[row][col+3] = f2bf(v.w);
  }
  __syncthreads();
  unsigned short* Ubg = (unsigned short*)(ws + OFF_UB) + (size_t)p * NS5 * ND;
#pragma unroll
  for (int i = 0; i < 4; ++i) {
    int f = tid + i * 256;               // 1024 granules: s = f>>4, g = f&15
    int s = f >> 4, g = f & 15;
    ushort8 o;
#pragma unroll
    for (int j = 0; j < 8; ++j) o[j] = ts[g * 8 + j][s];
    *(ushort8*)(Ubg + (size_t)s * ND + d0 + g * 8) = o;
  }
  if (tid < 16) {                        // proto row 64, this d-chunk
    const float* pr = protos + (size_t)p * ND + d0 + tid * 8;
    float4 v0 = *(const float4*)pr, v1 = *(const float4*)(pr + 4);
    ushort8 o;
    o[0]=f2bf(v0.x); o[1]=f2bf(v0.y); o[2]=f2bf(v0.z); o[3]=f2bf(v0.w);
    o[4]=f2bf(v1.x); o[5]=f2bf(v1.y); o[6]=f2bf(v1.z); o[7]=f2bf(v1.w);
    *(ushort8*)(Ubg + (size_t)64 * ND + d0 + tid * 8) = o;
  }
}

// ---------------------------------------------------------------------------
// k_gram: Ghat = Ub @ Ub^T via MFMA. 4x4 tiles -> Gb bf16; col 4 -> c fp32;
// (4,4) diag -> pn. grid 200 x 256. 80 KB LDS, granule-swizzled. (unchanged)
// ---------------------------------------------------------------------------
__global__ __launch_bounds__(256) void k_gram(float* __restrict__ ws) {
  const int p = blockIdx.x;
  __shared__ __align__(16) unsigned short ut[NS5 * ND];  // 80 KB
  const int tid = threadIdx.x, l = tid & 63, w = tid >> 6;
  const int lm = l & 15, lh = l >> 4;
  const unsigned short* ub =
      (const unsigned short*)(ws + OFF_UB) + (size_t)p * NS5 * ND;
#pragma unroll
  for (int i = 0; i < 20; ++i) {
    int f = tid + i * 256;
    int r = f >> 6;
    int gd = (f & 63) ^ (r & 15);
    *(ushort8*)(ut + (size_t)f * 8) = *(const ushort8*)(ub + (size_t)r * ND + gd * 8);
  }
  __syncthreads();
  const int ntile = (w == 0) ? 6 : 5;
  for (int idx = 0; idx < ntile; ++idx) {
    int tt = (idx == 5) ? 20 : (w + 4 * idx);
    int i1 = (tt == 20) ? 4 : tt / 5;
    int i2 = (tt == 20) ? 4 : tt % 5;
    f32x4 g = {0.f, 0.f, 0.f, 0.f};
#pragma unroll
    for (int ks = 0; ks < 16; ++ks) {
      int sl = (ks * 4 + lh) ^ lm;
      bf16x8 a = *(const bf16x8*)(ut + ((size_t)(i1 * 16 + lm) * 64 + sl) * 8);
      bf16x8 b = *(const bf16x8*)(ut + ((size_t)(i2 * 16 + lm) * 64 + sl) * 8);
      g = __builtin_amdgcn_mfma_f32_16x16x32_bf16(a, b, g, 0, 0, 0);
    }
    int col = i2 * 16 + lm;
    int row0 = i1 * 16 + lh * 4;
    if (i1 < 4 && i2 < 4) {
      unsigned short* Gbg = (unsigned short*)(ws + OFF_GB) + (size_t)p * 4096;
#pragma unroll
      for (int q = 0; q < 4; ++q) Gbg[(size_t)(row0 + q) * 64 + col] = f2bf(g[q]);
    } else if (i1 < 4 && i2 == 4 && lm == 0) {
#pragma unroll
      for (int q = 0; q < 4; ++q) ws[OFF_C + p * 64 + row0 + q] = g[q];
    } else if (tt == 20 && l == 0) {
      ws[OFF_PN + p] = g[0];
    }
  }
}

// ---------------------------------------------------------------------------
// k_main: grid (200, 8). Ub staged ONCE into 72 KB swizzled LDS; K-loop
// barrier-free (A from L2 to regs, B via ds_read). G + c in registers.
// Epilogue: tb bf16 overlays ut after the single barrier; GEMM2 MFMA; out.
// ---------------------------------------------------------------------------
__global__ __launch_bounds__(256, 2) void k_main(float* __restrict__ ws,
                                                 float* __restrict__ out)
{
  const int p = blockIdx.x;
  const int b0 = blockIdx.y * 128;
  __shared__ __align__(16) unsigned short ut[72 * 512];  // 73728 B
  unsigned short* tb = ut;                               // [128][72] overlay
  const int tid = threadIdx.x, l = tid & 63, w = tid >> 6;
  const int lm = l & 15, lh = l >> 4;

  const unsigned short* Xb = (const unsigned short*)(ws + OFF_XB) + (size_t)b0 * ND;
  const unsigned short* Ub = (const unsigned short*)(ws + OFF_UB) + (size_t)p * NS5 * ND;
  const unsigned short* Gbg = (const unsigned short*)(ws + OFF_GB) + (size_t)p * 4096;

  // ---- stage Ub rows 0..71 into ut, swizzled: LDS granule f holds data
  // granule (f&63)^(r&15) of row r=f>>6.  4608 granules, 18 waves-waves.
#pragma unroll
  for (int i = 0; i < 18; ++i) {
    int f = i * 256 + w * 64 + l;        // dest uniform part + lane
    int r = f >> 6, gd = (f & 63) ^ (r & 15);
    gl_lds16(Ub + (size_t)r * ND + gd * 8, ut + (size_t)(i * 256 + w * 64) * 8);
  }
  // c -> registers (per-lane: col j*16+lm)
  float cr[4];
#pragma unroll
  for (int j = 0; j < 4; ++j) cr[j] = ws[OFF_C + p * 64 + j * 16 + lm];

  asm volatile("s_waitcnt vmcnt(0) lgkmcnt(0)" ::: "memory");
  __builtin_amdgcn_s_barrier();

  // ---- GEMM1: barrier-free; per K-step: 4 A-loads + 10 ds_read + 20 MFMA
  const unsigned short* xr0 = Xb + (size_t)((w * 2 + 0) * 16 + lm) * ND;
  const unsigned short* xr1 = Xb + (size_t)((w * 2 + 1) * 16 + lm) * ND;
  f32x4 acc[2][5] = {};
#pragma unroll
  for (int it = 0; it < 8; ++it) {
#pragma unroll
    for (int ks = 0; ks < 2; ++ks) {
      const int gd = it * 8 + ks * 4 + lh;     // K-granule 0..63
      bf16x8 a0 = *(const bf16x8*)(xr0 + gd * 8);
      bf16x8 a1 = *(const bf16x8*)(xr1 + gd * 8);
#pragma unroll
      for (int j = 0; j < 4; ++j) {
        const int r = j * 16 + lm;             // r&15 == lm
        bf16x8 b = *(const bf16x8*)(ut + (size_t)(r * 64 + (gd ^ lm)) * 8);
        acc[0][j] = __builtin_amdgcn_mfma_f32_16x16x32_bf16(a0, b, acc[0][j], 0, 0, 0);
        acc[1][j] = __builtin_amdgcn_mfma_f32_16x16x32_bf16(a1, b, acc[1][j], 0, 0, 0);
      }
      {  // proto col-tile: rows clamped to 64..71 (lanes lm>=8 discarded)
        const int r = 64 + (lm & 7);           // r&15 == lm&7
        bf16x8 b = *(const bf16x8*)(ut + (size_t)(r * 64 + (gd ^ (lm & 7))) * 8);
        acc[0][4] = __builtin_amdgcn_mfma_f32_16x16x32_bf16(a0, b, acc[0][4], 0, 0, 0);
        acc[1][4] = __builtin_amdgcn_mfma_f32_16x16x32_bf16(a1, b, acc[1][4], 0, 0, 0);
      }
    }
  }

  // G-fragments -> registers (latency hidden under barrier + tb writes)
  bf16x8 gfrag[2][4];
#pragma unroll
  for (int ks = 0; ks < 2; ++ks)
#pragma unroll
    for (int j = 0; j < 4; ++j)
      gfrag[ks][j] = *(const bf16x8*)(Gbg + (size_t)(j * 16 + lm) * 64 + ks * 32 + lh * 8);

  __syncthreads();   // all waves done reading ut; tb overlay becomes safe

  // ---- epilogue 1: t = acc - c -> tb bf16 (wave-private rows); tn fp32
  float tn[2][4] = {};
  float xpr[2][4];
#pragma unroll
  for (int i = 0; i < 2; ++i) {
    int rbase = (w * 2 + i) * 16 + lh * 4;
#pragma unroll
    for (int j = 0; j < 4; ++j) {
      f32x4 v = acc[i][j];
      int col = j * 16 + lm;
#pragma unroll
      for (int q = 0; q < 4; ++q) {
        float t = v[q] - cr[j];
        tn[i][q] += t * t;
        tb[(size_t)(rbase + q) * 72 + col] = f2bf(t);
      }
    }
#pragma unroll
    for (int q = 0; q < 4; ++q) xpr[i][q] = acc[i][4][q];  // x.proto (lm==0)
  }

  // ---- GEMM2: H = tb @ G (B-frag = G rows, G symmetric) ----
  f32x4 acc2[2][4] = {};
#pragma unroll
  for (int ks = 0; ks < 2; ++ks)
#pragma unroll
    for (int i = 0; i < 2; ++i) {
      bf16x8 a = *(const bf16x8*)(tb + (size_t)((w*2+i)*16 + lm) * 72 + ks*32 + lh*8);
#pragma unroll
      for (int j = 0; j < 4; ++j)
        acc2[i][j] = __builtin_amdgcn_mfma_f32_16x16x32_bf16(a, gfrag[ks][j], acc2[i][j], 0, 0, 0);
    }

  // ---- tgt = sum_s2 H*t; reduce over lm; out = sqrt(q - 2tn + tgt) ----
  const float pnv = ws[OFF_PN + p];
#pragma unroll
  for (int i = 0; i < 2; ++i) {
    int rbase = (w * 2 + i) * 16 + lh * 4;
    float tgt[4] = {0.f, 0.f, 0.f, 0.f};
#pragma unroll
    for (int j = 0; j < 4; ++j) {
      int col = j * 16 + lm;
#pragma unroll
      for (int q = 0; q < 4; ++q)
        tgt[q] += acc2[i][j][q] * bf2f(tb[(size_t)(rbase + q) * 72 + col]);
    }
#pragma unroll
    for (int q = 0; q < 4; ++q) {
      float ta = tgt[q], tnv = tn[i][q];
#pragma unroll
      for (int m = 1; m <= 8; m <<= 1) {
        ta += __shfl_xor(ta, m);
        tnv += __shfl_xor(tnv, m);
      }
      tgt[q] = ta; tn[i][q] = tnv;
    }
    if (lm == 0) {
#pragma unroll
      for (int q = 0; q < 4; ++q) {
        int r = rbase + q;
        int bb = b0 + r;
        float qq = ws[OFF_XN + bb] - 2.f * xpr[i][q] + pnv;
        float v = qq - 2.f * tn[i][q] + tgt[q];
        out[(size_t)bb * NP + p] = sqrtf(fmaxf(v, 0.f));
      }
    }
  }
}

// ---------------------------------------------------------------------------
extern "C" void kernel_launch(void* const* d_in, const int* in_sizes, int n_in,
                              void* d_out, int out_size, void* d_ws, size_t ws_size,
                              hipStream_t stream) {
  const float* x      = (const float*)d_in[0];
  const float* protos = (const float*)d_in[1];
  const float* U      = (const float*)d_in[2];
  float* out = (float*)d_out;
  float* ws  = (float*)d_ws;   // needs 4,785,864 floats (~19.2 MB)

  k_conv<<<dim3(832),   dim3(256), 0, stream>>>(x, protos, U, ws);
  k_gram<<<dim3(NP),    dim3(256), 0, stream>>>(ws);
  k_main<<<dim3(NP, 8), dim3(256), 0, stream>>>(ws, out);
}

// Round 11
// 128.570 us; speedup vs baseline: 1.4104x; 1.0163x over previous
//
#include <hip/hip_runtime.h>
#include <math.h>

// out[b,p] = || (I - U_p U_p^T)(x_b - proto_p) ||,  B=1024 P=200 D=512 S=64
// t = U^T x - c, c = U^T proto; ||y||^2 = q - 2||t||^2 + t^T G t,
// q = ||x||^2 - 2 x.proto + ||proto||^2, G = U^T U (symmetric).
// k_main: Ub LDS-resident in two 36.9KB K-halves (4 blocks/CU); A-fragments
// stream from L2 through an explicit 2-deep register pipeline (no per-step
// barriers); B via ds_read; G + c in registers. 3 barriers total.

#define NB 1024
#define NP 200
#define ND 512
#define NS 64
#define NS5 80   // 64 U-cols + proto col + pad rows

// ws float offsets; total 4,785,864 floats (~19.2 MB) incl. 16-row overrun pad
#define OFF_C   0          // fp32 [200][64]  c = U^T proto
#define OFF_PN  12800      // fp32 [200]      ||proto||^2
#define OFF_XN  13000      // fp32 [1024]     ||x||^2
#define OFF_GB  14024      // bf16 [200][64][64]  G
#define OFF_XB  423624     // bf16 [1024][512]
#define OFF_UB  685768     // bf16 [200][80][512] (U^T | proto | junk)

typedef __attribute__((ext_vector_type(8))) short bf16x8;
typedef __attribute__((ext_vector_type(8))) unsigned short ushort8;
typedef __attribute__((ext_vector_type(4))) float f32x4;

__device__ __forceinline__ unsigned short f2bf(float f) {
  unsigned int u = __float_as_uint(f);
  u += 0x7fffu + ((u >> 16) & 1u);   // RNE
  return (unsigned short)(u >> 16);
}
__device__ __forceinline__ float bf2f(unsigned short h) {
  return __uint_as_float(((unsigned int)h) << 16);
}
// async global->LDS, 16B/lane; LDS dest = wave-uniform base + lane*16
__device__ __forceinline__ void gl_lds16(const void* g, void* l) {
  __builtin_amdgcn_global_load_lds(
      (const __attribute__((address_space(1))) unsigned int*)g,
      (__attribute__((address_space(3))) unsigned int*)l, 16, 0, 0);
}

// ---------------------------------------------------------------------------
// k_conv: grid 832. Blocks 0..799: transpose+convert U chunk (p = bid>>2,
// 128 d-rows) -> Ub bf16 [p][s][d] + proto row-64 segment. Blocks 800..831:
// convert 32 rows of x -> Xb bf16 + ||x||^2.   (unchanged)
// ---------------------------------------------------------------------------
__global__ __launch_bounds__(256) void k_conv(
    const float* __restrict__ x, const float* __restrict__ protos,
    const float* __restrict__ U, float* __restrict__ ws)
{
  const int bid = blockIdx.x, tid = threadIdx.x;
  if (bid >= 800) {
    const int b = (bid - 800) * 32 + (tid >> 3);
    const int cc = tid & 7;
    const float* src = x + (size_t)b * ND + cc * 64;
    unsigned short* dst = (unsigned short*)(ws + OFF_XB) + (size_t)b * ND + cc * 64;
    float s = 0.f;
#pragma unroll
    for (int i = 0; i < 8; ++i) {
      float4 v0 = *(const float4*)(src + i * 8);
      float4 v1 = *(const float4*)(src + i * 8 + 4);
      ushort8 o;
      o[0]=f2bf(v0.x); o[1]=f2bf(v0.y); o[2]=f2bf(v0.z); o[3]=f2bf(v0.w);
      o[4]=f2bf(v1.x); o[5]=f2bf(v1.y); o[6]=f2bf(v1.z); o[7]=f2bf(v1.w);
      *(ushort8*)(dst + i * 8) = o;
      s += v0.x*v0.x + v0.y*v0.y + v0.z*v0.z + v0.w*v0.w
         + v1.x*v1.x + v1.y*v1.y + v1.z*v1.z + v1.w*v1.w;
    }
    s += __shfl_xor(s, 1); s += __shfl_xor(s, 2); s += __shfl_xor(s, 4);
    if (cc == 0) ws[OFF_XN + b] = s;
    return;
  }
  const int p = bid >> 2, d0 = (bid & 3) * 128;
  __shared__ unsigned short ts[128][66];   // bf16, pad 66: column reads 2-way
#pragma unroll
  for (int i = 0; i < 8; ++i) {
    int row = (tid >> 4) + i * 16;
    int col = (tid & 15) * 4;
    float4 v = *(const float4*)(U + ((size_t)p * ND + d0 + row) * NS + col);
    ts[row][col] = f2bf(v.x); ts[row][col+1] = f2bf(v.y);
    ts[row][col+2] = f2bf(v.z); ts[row][col+3] = f2bf(v.w);
  }
  __syncthreads();
  unsigned short* Ubg = (unsigned short*)(ws + OFF_UB) + (size_t)p * NS5 * ND;
#pragma unroll
  for (int i = 0; i < 4; ++i) {
    int f = tid + i * 256;               // 1024 granules: s = f>>4, g = f&15
    int s = f >> 4, g = f & 15;
    ushort8 o;
#pragma unroll
    for (int j = 0; j < 8; ++j) o[j] = ts[g * 8 + j][s];
    *(ushort8*)(Ubg + (size_t)s * ND + d0 + g * 8) = o;
  }
  if (tid < 16) {                        // proto row 64, this d-chunk
    const float* pr = protos + (size_t)p * ND + d0 + tid * 8;
    float4 v0 = *(const float4*)pr, v1 = *(const float4*)(pr + 4);
    ushort8 o;
    o[0]=f2bf(v0.x); o[1]=f2bf(v0.y); o[2]=f2bf(v0.z); o[3]=f2bf(v0.w);
    o[4]=f2bf(v1.x); o[5]=f2bf(v1.y); o[6]=f2bf(v1.z); o[7]=f2bf(v1.w);
    *(ushort8*)(Ubg + (size_t)64 * ND + d0 + tid * 8) = o;
  }
}

// ---------------------------------------------------------------------------
// k_gram: Ghat = Ub @ Ub^T via MFMA. 4x4 tiles -> Gb bf16; col 4 -> c fp32;
// (4,4) diag -> pn. grid 200 x 256. 80 KB LDS, granule-swizzled. (unchanged)
// ---------------------------------------------------------------------------
__global__ __launch_bounds__(256) void k_gram(float* __restrict__ ws) {
  const int p = blockIdx.x;
  __shared__ __align__(16) unsigned short ut[NS5 * ND];  // 80 KB
  const int tid = threadIdx.x, l = tid & 63, w = tid >> 6;
  const int lm = l & 15, lh = l >> 4;
  const unsigned short* ub =
      (const unsigned short*)(ws + OFF_UB) + (size_t)p * NS5 * ND;
#pragma unroll
  for (int i = 0; i < 20; ++i) {
    int f = tid + i * 256;
    int r = f >> 6;
    int gd = (f & 63) ^ (r & 15);
    *(ushort8*)(ut + (size_t)f * 8) = *(const ushort8*)(ub + (size_t)r * ND + gd * 8);
  }
  __syncthreads();
  const int ntile = (w == 0) ? 6 : 5;
  for (int idx = 0; idx < ntile; ++idx) {
    int tt = (idx == 5) ? 20 : (w + 4 * idx);
    int i1 = (tt == 20) ? 4 : tt / 5;
    int i2 = (tt == 20) ? 4 : tt % 5;
    f32x4 g = {0.f, 0.f, 0.f, 0.f};
#pragma unroll
    for (int ks = 0; ks < 16; ++ks) {
      int sl = (ks * 4 + lh) ^ lm;
      bf16x8 a = *(const bf16x8*)(ut + ((size_t)(i1 * 16 + lm) * 64 + sl) * 8);
      bf16x8 b = *(const bf16x8*)(ut + ((size_t)(i2 * 16 + lm) * 64 + sl) * 8);
      g = __builtin_amdgcn_mfma_f32_16x16x32_bf16(a, b, g, 0, 0, 0);
    }
    int col = i2 * 16 + lm;
    int row0 = i1 * 16 + lh * 4;
    if (i1 < 4 && i2 < 4) {
      unsigned short* Gbg = (unsigned short*)(ws + OFF_GB) + (size_t)p * 4096;
#pragma unroll
      for (int q = 0; q < 4; ++q) Gbg[(size_t)(row0 + q) * 64 + col] = f2bf(g[q]);
    } else if (i1 < 4 && i2 == 4 && lm == 0) {
#pragma unroll
      for (int q = 0; q < 4; ++q) ws[OFF_C + p * 64 + row0 + q] = g[q];
    } else if (tt == 20 && l == 0) {
      ws[OFF_PN + p] = g[0];
    }
  }
}

// ---------------------------------------------------------------------------
// k_main: grid (200, 8). Ub in LDS as two 72x256 halves (36.9 KB -> 4 blk/CU).
// A-fragments: explicit 2-step register pipeline from L2 (no per-step waits).
// 16 steps x {2 A-loads, 5 ds_read_b128, 10 MFMA}; 3 barriers total.
// ---------------------------------------------------------------------------
__global__ __launch_bounds__(256, 3) void k_main(float* __restrict__ ws,
                                                 float* __restrict__ out)
{
  const int p = blockIdx.x;
  const int b0 = blockIdx.y * 128;
  __shared__ __align__(16) unsigned short ut[72 * 256];  // 36864 B
  unsigned short* tb = ut;                               // [128][72] overlay
  const int tid = threadIdx.x, l = tid & 63, w = tid >> 6;
  const int lm = l & 15, lh = l >> 4;

  const unsigned short* Xb = (const unsigned short*)(ws + OFF_XB) + (size_t)b0 * ND;
  const unsigned short* Ub = (const unsigned short*)(ws + OFF_UB) + (size_t)p * NS5 * ND;
  const unsigned short* Gbg = (const unsigned short*)(ws + OFF_GB) + (size_t)p * 4096;

  // stage one K-half of Ub (72 rows x 32 granules), swizzled:
  // LDS slot (f&31) of row f>>5 holds data granule (f&31)^(r&15).
  auto stageHalf = [&](int h) {
#pragma unroll
    for (int i = 0; i < 9; ++i) {
      int f = i * 256 + w * 64 + l;        // 0..2303
      int r = f >> 5, gd = (f & 31) ^ (r & 15);
      gl_lds16(Ub + (size_t)r * ND + h * 256 + gd * 8,
               ut + (size_t)(i * 256 + w * 64) * 8);
    }
  };

  const unsigned short* xr0 = Xb + (size_t)((w * 2 + 0) * 16 + lm) * ND;
  const unsigned short* xr1 = Xb + (size_t)((w * 2 + 1) * 16 + lm) * ND;

  stageHalf(0);
  float cr[4];
#pragma unroll
  for (int j = 0; j < 4; ++j) cr[j] = ws[OFF_C + p * 64 + j * 16 + lm];

  // A-pipeline prologue: steps u=0,1 (u = h*8+s; granule = u*4 + lh)
  bf16x8 pa0[3], pa1[3];
  pa0[0] = *(const bf16x8*)(xr0 + (0 * 4 + lh) * 8);
  pa1[0] = *(const bf16x8*)(xr1 + (0 * 4 + lh) * 8);
  pa0[1] = *(const bf16x8*)(xr0 + (1 * 4 + lh) * 8);
  pa1[1] = *(const bf16x8*)(xr1 + (1 * 4 + lh) * 8);

  asm volatile("s_waitcnt vmcnt(0) lgkmcnt(0)" ::: "memory");
  __builtin_amdgcn_s_barrier();

  // ---- GEMM1: wave w owns rows 32w..32w+31 (2 row-tiles) x 5 col-tiles ----
  f32x4 acc[2][5] = {};
#pragma unroll
  for (int h = 0; h < 2; ++h) {
#pragma unroll
    for (int s = 0; s < 8; ++s) {
      const int u = h * 8 + s;
      if (u < 14) {                        // prefetch step u+2 (cross-half ok)
        pa0[(u + 2) % 3] = *(const bf16x8*)(xr0 + ((u + 2) * 4 + lh) * 8);
        pa1[(u + 2) % 3] = *(const bf16x8*)(xr1 + ((u + 2) * 4 + lh) * 8);
      }
      const int sl = s * 4 + lh;           // local K-granule 0..31
      bf16x8 a0 = pa0[u % 3], a1 = pa1[u % 3];
#pragma unroll
      for (int j = 0; j < 4; ++j) {
        const int r = j * 16 + lm;         // r&15 == lm
        bf16x8 b = *(const bf16x8*)(ut + (size_t)(r * 32 + (sl ^ lm)) * 8);
        acc[0][j] = __builtin_amdgcn_mfma_f32_16x16x32_bf16(a0, b, acc[0][j], 0, 0, 0);
        acc[1][j] = __builtin_amdgcn_mfma_f32_16x16x32_bf16(a1, b, acc[1][j], 0, 0, 0);
      }
      {  // proto col-tile: rows 64..71 (r&15 == lm&7); lanes lm>=8 discarded
        const int r = 64 + (lm & 7);
        bf16x8 b = *(const bf16x8*)(ut + (size_t)(r * 32 + (sl ^ (lm & 7))) * 8);
        acc[0][4] = __builtin_amdgcn_mfma_f32_16x16x32_bf16(a0, b, acc[0][4], 0, 0, 0);
        acc[1][4] = __builtin_amdgcn_mfma_f32_16x16x32_bf16(a1, b, acc[1][4], 0, 0, 0);
      }
    }
    if (h == 0) {
      __builtin_amdgcn_s_barrier();        // all waves done reading half 0
      stageHalf(1);
      asm volatile("s_waitcnt vmcnt(0)" ::: "memory");
      __builtin_amdgcn_s_barrier();
    }
  }

  // G-fragments -> registers (latency hidden under barrier + tb writes)
  bf16x8 gfrag[2][4];
#pragma unroll
  for (int ks = 0; ks < 2; ++ks)
#pragma unroll
    for (int j = 0; j < 4; ++j)
      gfrag[ks][j] = *(const bf16x8*)(Gbg + (size_t)(j * 16 + lm) * 64 + ks * 32 + lh * 8);

  __syncthreads();   // all waves done reading ut; tb overlay becomes safe

  // ---- epilogue 1: t = acc - c -> tb bf16 (wave-private rows); tn fp32
  float tn[2][4] = {};
  float xpr[2][4];
#pragma unroll
  for (int i = 0; i < 2; ++i) {
    int rbase = (w * 2 + i) * 16 + lh * 4;
#pragma unroll
    for (int j = 0; j < 4; ++j) {
      f32x4 v = acc[i][j];
      int col = j * 16 + lm;
#pragma unroll
      for (int q = 0; q < 4; ++q) {
        float t = v[q] - cr[j];
        tn[i][q] += t * t;
        tb[(size_t)(rbase + q) * 72 + col] = f2bf(t);
      }
    }
#pragma unroll
    for (int q = 0; q < 4; ++q) xpr[i][q] = acc[i][4][q];  // x.proto (lm==0)
  }

  // ---- GEMM2: H = tb @ G (B-frag = G rows, G symmetric) ----
  f32x4 acc2[2][4] = {};
#pragma unroll
  for (int ks = 0; ks < 2; ++ks)
#pragma unroll
    for (int i = 0; i < 2; ++i) {
      bf16x8 a = *(const bf16x8*)(tb + (size_t)((w*2+i)*16 + lm) * 72 + ks*32 + lh*8);
#pragma unroll
      for (int j = 0; j < 4; ++j)
        acc2[i][j] = __builtin_amdgcn_mfma_f32_16x16x32_bf16(a, gfrag[ks][j], acc2[i][j], 0, 0, 0);
    }

  // ---- tgt = sum_s2 H*t; reduce over lm; out = sqrt(q - 2tn + tgt) ----
  const float pnv = ws[OFF_PN + p];
#pragma unroll
  for (int i = 0; i < 2; ++i) {
    int rbase = (w * 2 + i) * 16 + lh * 4;
    float tgt[4] = {0.f, 0.f, 0.f, 0.f};
#pragma unroll
    for (int j = 0; j < 4; ++j) {
      int col = j * 16 + lm;
#pragma unroll
      for (int q = 0; q < 4; ++q)
        tgt[q] += acc2[i][j][q] * bf2f(tb[(size_t)(rbase + q) * 72 + col]);
    }
#pragma unroll
    for (int q = 0; q < 4; ++q) {
      float ta = tgt[q], tnv = tn[i][q];
#pragma unroll
      for (int m = 1; m <= 8; m <<= 1) {
        ta += __shfl_xor(ta, m);
        tnv += __shfl_xor(tnv, m);
      }
      tgt[q] = ta; tn[i][q] = tnv;
    }
    if (lm == 0) {
#pragma unroll
      for (int q = 0; q < 4; ++q) {
        int r = rbase + q;
        int bb = b0 + r;
        float qq = ws[OFF_XN + bb] - 2.f * xpr[i][q] + pnv;
        float v = qq - 2.f * tn[i][q] + tgt[q];
        out[(size_t)bb * NP + p] = sqrtf(fmaxf(v, 0.f));
      }
    }
  }
}

// ---------------------------------------------------------------------------
extern "C" void kernel_launch(void* const* d_in, const int* in_sizes, int n_in,
                              void* d_out, int out_size, void* d_ws, size_t ws_size,
                              hipStream_t stream) {
  const float* x      = (const float*)d_in[0];
  const float* protos = (const float*)d_in[1];
  const float* U      = (const float*)d_in[2];
  float* out = (float*)d_out;
  float* ws  = (float*)d_ws;   // needs 4,785,864 floats (~19.2 MB)

  k_conv<<<dim3(832),   dim3(256), 0, stream>>>(x, protos, U, ws);
  k_gram<<<dim3(NP),    dim3(256), 0, stream>>>(ws);
  k_main<<<dim3(NP, 8), dim3(256), 0, stream>>>(ws, out);
}